// Round 4
// baseline (163.760 us; speedup 1.0000x reference)
//
#include <hip/hip_runtime.h>
#include <math.h>

#define L_DIM   8192
#define NCH     64
#define M_TOT_F 262144.0f
#define EPS_F   1e-5f
#define GBLK    512
#define GTPB    8     // gram tiles per block: 512*8 = 4096
#define ABLK    512
#define ATPB    8     // apply tiles per block: 512*8 = 4096

typedef float f32x4 __attribute__((ext_vector_type(4)));
typedef short bf16x8 __attribute__((ext_vector_type(8)));

union U8 { unsigned u[4]; bf16x8 v; };

// split two fp32 into packed bf16 hi (truncated) and bf16 lo (residual)
__device__ __forceinline__ void cvt2(float f0, float f1, unsigned& h, unsigned& l) {
    unsigned u0 = __float_as_uint(f0), u1 = __float_as_uint(f1);
    h = (u0 >> 16) | (u1 & 0xFFFF0000u);
    float r0 = f0 - __uint_as_float(u0 & 0xFFFF0000u);
    float r1 = f1 - __uint_as_float(u1 & 0xFFFF0000u);
    l = (__float_as_uint(r0) >> 16) | (__float_as_uint(r1) & 0xFFFF0000u);
}

__device__ __forceinline__ void split16(float v, unsigned short& h, unsigned short& l) {
    unsigned u = __float_as_uint(v);
    h = (unsigned short)(u >> 16);
    float r = v - __uint_as_float(u & 0xFFFF0000u);
    l = (unsigned short)(__float_as_uint(r) >> 16);
}

__device__ __forceinline__ float b2f(unsigned short h) {
    return __uint_as_float(((unsigned)h) << 16);
}

__device__ __forceinline__ f32x4 mfma16(bf16x8 a, bf16x8 b, f32x4 c) {
    return __builtin_amdgcn_mfma_f32_16x16x32_bf16(a, b, c, 0, 0, 0);
}

__device__ __forceinline__ f32x4 fzero() {
    f32x4 z; z[0] = 0.f; z[1] = 0.f; z[2] = 0.f; z[3] = 0.f; return z;
}

// ---------------- K1: gram partials, accumulated via device-scope atomicAdd ----------
__global__ __launch_bounds__(256) void gram_kernel(const float* __restrict__ X,
                                                   float* __restrict__ ws) {
    // fragment-order LDS: chunk c = ((rowgrp*2 + khalf)*4 + q)*16 + m ; 8 shorts per chunk
    __shared__ __align__(16) unsigned short hfrag[2][4096];
    __shared__ __align__(16) unsigned short lfrag[2][4096];
    const int tid  = threadIdx.x;
    const int w    = tid >> 6;
    const int lane = tid & 63;
    const int m    = lane & 15;
    const int q    = lane >> 4;
    const int row  = 16 * w + m;

    f32x4 acc1[4], acc2[4];
#pragma unroll
    for (int nb = 0; nb < 4; ++nb) { acc1[nb] = fzero(); acc2[nb] = fzero(); }
    float sacc = 0.f;

    const int tile0 = blockIdx.x * GTPB;
    float4 v[4];
    {
        int t0 = tile0;
        const float* src = X + ((size_t)((t0 >> 7) * NCH + row)) * L_DIM + ((t0 & 127) << 6) + 8 * q;
        v[0] = *(const float4*)(src);
        v[1] = *(const float4*)(src + 4);
        v[2] = *(const float4*)(src + 32);
        v[3] = *(const float4*)(src + 36);
    }

    for (int t = 0; t < GTPB; ++t) {
        const int p = t & 1;
#pragma unroll
        for (int i = 0; i < 4; ++i) sacc += v[i].x + v[i].y + v[i].z + v[i].w;

        bf16x8 Ah[2], Al[2];
#pragma unroll
        for (int k = 0; k < 2; ++k) {
            U8 H, L;
            cvt2(v[2 * k].x,     v[2 * k].y,     H.u[0], L.u[0]);
            cvt2(v[2 * k].z,     v[2 * k].w,     H.u[1], L.u[1]);
            cvt2(v[2 * k + 1].x, v[2 * k + 1].y, H.u[2], L.u[2]);
            cvt2(v[2 * k + 1].z, v[2 * k + 1].w, H.u[3], L.u[3]);
            Ah[k] = H.v; Al[k] = L.v;
            int chunk = ((w * 2 + k) * 4 + q) * 16 + m;
            *(bf16x8*)&hfrag[p][chunk * 8] = H.v;
            *(bf16x8*)&lfrag[p][chunk * 8] = L.v;
        }

        if (t + 1 < GTPB) {
            int tn = tile0 + t + 1;
            const float* src = X + ((size_t)((tn >> 7) * NCH + row)) * L_DIM + ((tn & 127) << 6) + 8 * q;
            v[0] = *(const float4*)(src);
            v[1] = *(const float4*)(src + 4);
            v[2] = *(const float4*)(src + 32);
            v[3] = *(const float4*)(src + 36);
        }
        __syncthreads();

#pragma unroll
        for (int k = 0; k < 2; ++k)
#pragma unroll
            for (int nb = 0; nb < 4; ++nb) {
                int chunk = ((nb * 2 + k) * 4 + q) * 16 + m;
                bf16x8 bh = *(const bf16x8*)&hfrag[p][chunk * 8];
                bf16x8 bl = *(const bf16x8*)&lfrag[p][chunk * 8];
                acc1[nb] = mfma16(Ah[k], bh, acc1[nb]);
                acc2[nb] = mfma16(Ah[k], bl, acc2[nb]);
            }
    }

    // device-scope atomic accumulation (coherent across XCDs by definition)
#pragma unroll
    for (int nb = 0; nb < 4; ++nb)
#pragma unroll
        for (int r = 0; r < 4; ++r) {
            int grow = 16 * w + 4 * q + r;
            int gcol = 16 * nb + m;
            atomicAdd(&ws[grow * 64 + gcol],        acc1[nb][r]);
            atomicAdd(&ws[4096 + grow * 64 + gcol], acc2[nb][r]);
        }
    sacc += __shfl_xor(sacc, 16);
    sacc += __shfl_xor(sacc, 32);
    if (q == 0) atomicAdd(&ws[8192 + row], sacc);
}

// ---------------- K2: per-block redundant Newton-Schulz + apply ----------------------
// ---- LDS arena offsets (79 KB, phase-aliased) ----
#define OFF_A      0        // apply dbuf planes [2][4096] shorts x2; NS aliases T1h/T1l/T2h
#define OFF_T1H    0
#define OFF_T1L    9216
#define OFF_T2H    18432
#define OFF_PH     32768
#define OFF_PL     41984
#define OFF_SH     51200    // after NS: wmh (8192 B) + bias (256 B @ +8192)
#define OFF_SL     60416    // after NS: wml
#define OFF_T2L    69632
#define OFF_MU     78848
#define OFF_SCAL   79104
#define SM_BYTES   79120

__device__ __forceinline__ void mm_core(f32x4* acc,
                                        const unsigned short* Xh, const unsigned short* Xl,
                                        const unsigned short* Yh, const unsigned short* Yl,
                                        int w, int m, int q) {
#pragma unroll
    for (int k0 = 0; k0 < 64; k0 += 32) {
        bf16x8 xh = *(const bf16x8*)&Xh[(16 * w + m) * 72 + k0 + 8 * q];
        bf16x8 xl = *(const bf16x8*)&Xl[(16 * w + m) * 72 + k0 + 8 * q];
#pragma unroll
        for (int nb = 0; nb < 4; ++nb) {
            bf16x8 yh = *(const bf16x8*)&Yh[(16 * nb + m) * 72 + k0 + 8 * q];
            bf16x8 yl = *(const bf16x8*)&Yl[(16 * nb + m) * 72 + k0 + 8 * q];
            acc[nb] = mfma16(xh, yh, acc[nb]);
            acc[nb] = mfma16(xh, yl, acc[nb]);
            acc[nb] = mfma16(xl, yh, acc[nb]);
        }
    }
}

__device__ __forceinline__ void mm_pl(unsigned short* Dh, unsigned short* Dl,
                                      const unsigned short* Xh, const unsigned short* Xl,
                                      const unsigned short* Yh, const unsigned short* Yl,
                                      int w, int m, int q) {
    f32x4 acc[4];
#pragma unroll
    for (int nb = 0; nb < 4; ++nb) acc[nb] = fzero();
    mm_core(acc, Xh, Xl, Yh, Yl, w, m, q);
#pragma unroll
    for (int nb = 0; nb < 4; ++nb)
#pragma unroll
        for (int r = 0; r < 4; ++r) {
            int row = 16 * w + 4 * q + r, col = 16 * nb + m;
            unsigned short h, l;
            split16(acc[nb][r], h, l);
            Dh[row * 72 + col] = h;
            Dl[row * 72 + col] = l;
        }
}

__global__ __launch_bounds__(256, 2) void nsapply_kernel(const float* __restrict__ X,
                                                         float* __restrict__ Y,
                                                         const float* __restrict__ ws) {
    __shared__ __align__(16) unsigned char smem[SM_BYTES];
    const int tid  = threadIdx.x;
    const int bid  = blockIdx.x;
    const int w    = tid >> 6;
    const int lane = tid & 63;
    const int m    = lane & 15;
    const int q    = lane >> 4;
    const int cp   = tid & 31;
    const int lg   = tid >> 5;

    unsigned short* hfrag = (unsigned short*)(smem + OFF_A);          // [2][4096]
    unsigned short* lfrag = (unsigned short*)(smem + OFF_A + 16384);  // [2][4096]
    unsigned short* Ph  = (unsigned short*)(smem + OFF_PH);
    unsigned short* Pl  = (unsigned short*)(smem + OFF_PL);
    unsigned short* Sh  = (unsigned short*)(smem + OFF_SH);
    unsigned short* Sl  = (unsigned short*)(smem + OFF_SL);
    unsigned short* T1h = (unsigned short*)(smem + OFF_T1H);
    unsigned short* T1l = (unsigned short*)(smem + OFF_T1L);
    unsigned short* T2h = (unsigned short*)(smem + OFF_T2H);
    unsigned short* T2l = (unsigned short*)(smem + OFF_T2L);
    float* mu   = (float*)(smem + OFF_MU);
    float* scal = (float*)(smem + OFF_SCAL);
    unsigned short* wmh = (unsigned short*)(smem + OFF_SH);           // overwrites Sh
    unsigned short* wml = (unsigned short*)(smem + OFF_SL);           // overwrites Sl
    float* bias = (float*)(smem + OFF_SH + 8192);
    const float inv_m = 1.0f / M_TOT_F;

    // hoist first apply tile's global loads ahead of NS (latency hidden under NS)
    float4 va[2], vb[2];
    {
        int tile = bid * ATPB;
        const float* xb = X + (size_t)(tile >> 7) * (NCH * L_DIM) + ((tile & 127) << 6)
                          + (size_t)(2 * cp) * L_DIM + 4 * lg;
#pragma unroll
        for (int ss = 0; ss < 2; ++ss) {
            va[ss] = *(const float4*)(xb + 32 * ss);
            vb[ss] = *(const float4*)(xb + 32 * ss + L_DIM);
        }
    }

    // ---------- NS phase (redundant per block; ws is coherent: K1->K2 boundary) -------
    if (tid < 64) mu[tid] = ws[8192 + tid] * inv_m;
    __syncthreads();

    if (tid < 64) {
        int e = tid * 65;  // diagonal of G1/G2
        float g  = (ws[e] + 2.0f * ws[4096 + e]) * inv_m;
        float sd = g - mu[tid] * mu[tid] + EPS_F;
#pragma unroll
        for (int off = 32; off >= 1; off >>= 1) sd += __shfl_xor(sd, off);
        if (tid == 0) { scal[0] = 1.0f / sd; scal[1] = sqrtf(1.0f / sd); }
    }
    __syncthreads();
    const float rTr = scal[0];

    for (int e = tid; e < 4096; e += 256) {
        int i = e >> 6, j = e & 63;
        float g   = (ws[e] + ws[4096 + e] + ws[4096 + (j << 6) + i]) * inv_m;
        float sig = g - mu[i] * mu[j] + ((i == j) ? EPS_F : 0.f);
        float sn  = sig * rTr;
        unsigned short h, l;
        split16(sn, h, l);
        Sh[i * 72 + j] = h; Sl[i * 72 + j] = l;
        float pv = ((i == j) ? 1.5f : 0.f) - 0.5f * sn;   // closed-form NS iter 1
        split16(pv, h, l);
        Ph[i * 72 + j] = h; Pl[i * 72 + j] = l;
    }
    __syncthreads();

    for (int it = 0; it < 4; ++it) {
        mm_pl(T1h, T1l, Ph, Pl, Ph, Pl, w, m, q);    // T1 = P^2
        __syncthreads();
        mm_pl(T2h, T2l, T1h, T1l, Ph, Pl, w, m, q);  // T2 = P^3
        __syncthreads();
        f32x4 acc[4];
#pragma unroll
        for (int nb = 0; nb < 4; ++nb) acc[nb] = fzero();
        mm_core(acc, T2h, T2l, Sh, Sl, w, m, q);     // U = P^3 * S_N
#pragma unroll
        for (int nb = 0; nb < 4; ++nb)
#pragma unroll
            for (int r = 0; r < 4; ++r) {
                int row = 16 * w + 4 * q + r, col = 16 * nb + m;
                int pidx = row * 72 + col;
                float pold = b2f(Ph[pidx]) + b2f(Pl[pidx]);
                float pv = 1.5f * pold - 0.5f * acc[nb][r];
                unsigned short h, l;
                split16(pv, h, l);
                Ph[pidx] = h; Pl[pidx] = l;
            }
        __syncthreads();
    }

    const float s = scal[1];
    if (tid < 64) {
        float a = 0.f;
#pragma unroll 8
        for (int k = 0; k < 64; ++k)
            a += (b2f(Ph[tid * 72 + k]) + b2f(Pl[tid * 72 + k])) * mu[k];
        bias[tid] = -a * s;
    }
    for (int e = tid; e < 4096; e += 256) {
        int i = e >> 6, j = e & 63;
        float v = (b2f(Ph[i * 72 + j]) + b2f(Pl[i * 72 + j])) * s;
        unsigned short h, l;
        split16(v, h, l);
        wmh[e] = h;    // row-major [c][k] stride 64 — A-fragment order for apply
        wml[e] = l;
    }
    __syncthreads();

    // ---------- apply phase: Y = wm @ x + bias ----------
    bf16x8 Ah[2], Al[2];
#pragma unroll
    for (int kk = 0; kk < 2; ++kk) {
        Ah[kk] = *(const bf16x8*)&wmh[(16 * w + m) * 64 + 32 * kk + 8 * q];
        Al[kk] = *(const bf16x8*)&wml[(16 * w + m) * 64 + 32 * kk + 8 * q];
    }
    const float4 bias4 = *(const float4*)&bias[16 * w + 4 * q];

    for (int t = 0; t < ATPB; ++t) {
        int tile = bid * ATPB + t;
        int bidx = tile >> 7;
        int l0   = (tile & 127) << 6;
        const int p = t & 1;
        unsigned* hw2 = (unsigned*)(hfrag + p * 4096);
        unsigned* lw2 = (unsigned*)(lfrag + p * 4096);

#pragma unroll
        for (int ss = 0; ss < 2; ++ss) {
            float fa[4], fb[4];
            *(float4*)fa = va[ss];
            *(float4*)fb = vb[ss];
#pragma unroll
            for (int i = 0; i < 4; ++i) {
                int l = 4 * lg + 32 * ss + i;
                unsigned h, lo2;
                cvt2(fa[i], fb[i], h, lo2);
                int widx = l * 32 + (((cp >> 2) ^ (l & 7)) << 2) + (cp & 3);
                hw2[widx] = h;
                lw2[widx] = lo2;
            }
        }

        if (t + 1 < ATPB) {
            int tn = tile + 1;
            const float* xb = X + (size_t)(tn >> 7) * (NCH * L_DIM) + ((tn & 127) << 6)
                              + (size_t)(2 * cp) * L_DIM + 4 * lg;
#pragma unroll
            for (int ss = 0; ss < 2; ++ss) {
                va[ss] = *(const float4*)(xb + 32 * ss);
                vb[ss] = *(const float4*)(xb + 32 * ss + L_DIM);
            }
        }
        __syncthreads();

        f32x4 acc[4];
#pragma unroll
        for (int nb = 0; nb < 4; ++nb) {
            acc[nb][0] = bias4.x; acc[nb][1] = bias4.y;
            acc[nb][2] = bias4.z; acc[nb][3] = bias4.w;
        }
#pragma unroll
        for (int kk = 0; kk < 2; ++kk)
#pragma unroll
            for (int nb = 0; nb < 4; ++nb) {
                int l = 16 * nb + m;
                int saddr = l * 64 + ((((4 * kk + q) ^ (l & 7))) << 3);
                bf16x8 bh = *(const bf16x8*)&hfrag[p * 4096 + saddr];
                bf16x8 bl = *(const bf16x8*)&lfrag[p * 4096 + saddr];
                acc[nb] = mfma16(Ah[kk], bh, acc[nb]);
                acc[nb] = mfma16(Ah[kk], bl, acc[nb]);
                acc[nb] = mfma16(Al[kk], bh, acc[nb]);
            }

#pragma unroll
        for (int nb = 0; nb < 4; ++nb)
#pragma unroll
            for (int rr = 0; rr < 4; ++rr)
                Y[((size_t)bidx * NCH + 16 * w + 4 * q + rr) * L_DIM + l0 + 16 * nb + m] = acc[nb][rr];
    }
}

extern "C" void kernel_launch(void* const* d_in, const int* in_sizes, int n_in,
                              void* d_out, int out_size, void* d_ws, size_t ws_size,
                              hipStream_t stream) {
    const float* X = (const float*)d_in[0];
    float* Y  = (float*)d_out;
    float* ws = (float*)d_ws;

    hipMemsetAsync(ws, 0, 8256 * sizeof(float), stream);
    hipLaunchKernelGGL(gram_kernel,    dim3(GBLK), dim3(256), 0, stream, X, ws);
    hipLaunchKernelGGL(nsapply_kernel, dim3(ABLK), dim3(256), 0, stream, X, Y, ws);
}